// Round 17
// baseline (134.293 us; speedup 1.0000x reference)
//
#include <hip/hip_runtime.h>

#define NF 64
#define NBKMAX 512   // buckets of 256 nodes; n=100K -> 391 buckets
#define CHUNK 4096
#define CAP   4096   // slack capacity per bucket (mean 3070, +18 sigma)

typedef __attribute__((ext_vector_type(8))) short bf16x8;
typedef __attribute__((ext_vector_type(4))) float f32x4;

// bf16 helpers (RNE)
__device__ __forceinline__ unsigned short f2bf(float f) {
    union { float f; unsigned u; } c; c.f = f;
    unsigned u = c.u;
    return (unsigned short)((u + 0x7FFFu + ((u >> 16) & 1u)) >> 16);
}
__device__ __forceinline__ float bf2f1(unsigned short v) {
    union { unsigned u; float f; } c; c.u = ((unsigned)v) << 16;
    return c.f;
}
__device__ __forceinline__ float2 bfp2(unsigned v) {
    union { unsigned u; float f; } lo, hi;
    lo.u = v << 16;
    hi.u = v & 0xffff0000u;
    return make_float2(lo.f, hi.f);
}

// ---------------- prep: zero bcnt + W1/W2 hi/lo transpose-split ----------------
__global__ __launch_bounds__(256) void k_prep(int* __restrict__ bcnt, int nbk,
                                              const float* __restrict__ W1,
                                              unsigned short* __restrict__ wt1h,
                                              unsigned short* __restrict__ wt1l,
                                              const float* __restrict__ W2,
                                              unsigned short* __restrict__ wt2h,
                                              unsigned short* __restrict__ wt2l) {
    int idx = blockIdx.x * 256 + threadIdx.x;
    if (idx < 512) {
        if (idx < nbk) bcnt[idx] = 0;
    } else if (idx < 512 + 128 * 64) {
        int e = idx - 512;                 // W1: [128][64]
        int k = e >> 6, col = e & 63;
        float w = W1[e];
        unsigned short h = f2bf(w);
        wt1h[col * 128 + k] = h;
        wt1l[col * 128 + k] = f2bf(w - bf2f1(h));
    } else if (idx < 512 + 128 * 64 + 64 * 64) {
        int e = idx - 512 - 128 * 64;      // W2: [64][64]
        int k = e >> 6, col = e & 63;
        float w = W2[e];
        unsigned short h = f2bf(w);
        wt2h[col * 64 + k] = h;
        wt2l[col * 64 + k] = f2bf(w - bf2f1(h));
    }
}

// ---------------- GEMM core: A direct global->reg (no LDS, no per-step barrier) -------
__device__ __forceinline__ void load8f(const float* A, bool ok, size_t off, float* v) {
    if (ok) {
        float4 a = *(const float4*)&A[off];
        float4 b = *(const float4*)&A[off + 4];
        v[0]=a.x; v[1]=a.y; v[2]=a.z; v[3]=a.w;
        v[4]=b.x; v[5]=b.y; v[6]=b.z; v[7]=b.w;
    } else { for (int j = 0; j < 8; ++j) v[j] = 0.f; }
}

template<int K>
__device__ __forceinline__ void stage_w(const unsigned short* __restrict__ Wt_hi_g,
                                        const unsigned short* __restrict__ Wt_lo_g,
                                        unsigned short* __restrict__ sWh,
                                        unsigned short* __restrict__ sWl, int tid, int nthr) {
    constexpr int KS = K / 8, SM = KS - 1;
    for (int idx = tid; idx < 64 * KS; idx += nthr) {
        int col = idx / KS, slot = idx % KS;
        int d = col * K + 8 * (slot ^ (col & SM));
        *(uint4*)&sWh[d] = *(const uint4*)&Wt_hi_g[col * K + slot * 8];
        *(uint4*)&sWl[d] = *(const uint4*)&Wt_lo_g[col * K + slot * 8];
    }
}

// ---------------- fused: edge bucket-scatter (packed 4B) PARALLEL WITH mgemm<128> -----
struct ScatS {
    unsigned stage[CHUNK];          // (src<<8)|(dst&255)
    unsigned short stb[CHUNK];      // bucket = dst>>8
    int hist[NBKMAX];
    int base[NBKMAX];
};                                   // 28 KB
struct GemmS {
    unsigned short sWh[64 * 128];    // 16 KB
    unsigned short sWl[64 * 128];    // 16 KB
};
union USmem { ScatS s; GemmS g; };   // 32 KB

__global__ __launch_bounds__(256) void k_scat_gemm(
        const int* __restrict__ src, const int* __restrict__ dst,
        int* __restrict__ bcnt, unsigned* __restrict__ pairs4, int E, int nbk, int nscat,
        const float* __restrict__ A,
        const unsigned short* __restrict__ Wt_hi_g, const unsigned short* __restrict__ Wt_lo_g,
        unsigned short* __restrict__ out, int n) {
    __shared__ USmem u;
    const int tid = threadIdx.x;

    if ((int)blockIdx.x < nscat) {
        // ---- scatter path ----
        int e0 = blockIdx.x * CHUNK;
        int cnt = E - e0; if (cnt > CHUNK) cnt = CHUNK;
        for (int i = tid; i < nbk; i += 256) u.s.hist[i] = 0;
        __syncthreads();
        for (int i = tid; i < cnt; i += 256) {
            int s = src[e0 + i], d = dst[e0 + i];
            u.s.stage[i] = ((unsigned)s << 8) | ((unsigned)d & 255u);
            u.s.stb[i]   = (unsigned short)(((unsigned)d) >> 8);
            atomicAdd(&u.s.hist[((unsigned)d) >> 8], 1);
        }
        __syncthreads();
        for (int i = tid; i < nbk; i += 256) {
            int c = u.s.hist[i];
            u.s.base[i] = c ? atomicAdd(&bcnt[i], c) : 0;
            u.s.hist[i] = 0;   // reuse as local cursor
        }
        __syncthreads();
        for (int i = tid; i < cnt; i += 256) {
            int b = u.s.stb[i];
            int off = u.s.base[b] + atomicAdd(&u.s.hist[b], 1);
            if (off < CAP) pairs4[(size_t)b * CAP + off] = u.s.stage[i];
        }
        return;
    }

    // ---- mgemm<128,float> path ----
    constexpr int K = 128;
    constexpr int KS = K / 8, SM = KS - 1, NS = K / 32;
    const int rb = ((int)blockIdx.x - nscat) * 64;
    stage_w<128>(Wt_hi_g, Wt_lo_g, u.g.sWh, u.g.sWl, tid, 256);
    __syncthreads();

    const int w = tid >> 6, l = tid & 63;
    const int lr = l & 15, lg = l >> 4;
    const int arow = rb + w * 16 + lr;
    const bool ok = arow < n;

    float v[NS][8];
    #pragma unroll
    for (int s = 0; s < NS; ++s)
        load8f(A, ok, (size_t)arow * K + s * 32 + lg * 8, v[s]);

    f32x4 acc[4] = {};
    #pragma unroll
    for (int s = 0; s < NS; ++s) {
        unsigned short h8[8], l8[8];
        #pragma unroll
        for (int j = 0; j < 8; ++j) {
            h8[j] = f2bf(v[s][j]);
            l8[j] = f2bf(v[s][j] - bf2f1(h8[j]));
        }
        const bf16x8 ah = *(const bf16x8*)h8;
        const bf16x8 al = *(const bf16x8*)l8;
        #pragma unroll
        for (int ct = 0; ct < 4; ++ct) {
            int col  = ct * 16 + lr;
            int boff = col * K + 8 * ((s * 4 + lg) ^ (col & SM));
            const bf16x8 bh = *(const bf16x8*)&u.g.sWh[boff];
            const bf16x8 bl = *(const bf16x8*)&u.g.sWl[boff];
            acc[ct] = __builtin_amdgcn_mfma_f32_16x16x32_bf16(ah, bh, acc[ct], 0, 0, 0);
            acc[ct] = __builtin_amdgcn_mfma_f32_16x16x32_bf16(ah, bl, acc[ct], 0, 0, 0);
            acc[ct] = __builtin_amdgcn_mfma_f32_16x16x32_bf16(al, bh, acc[ct], 0, 0, 0);
        }
    }
    #pragma unroll
    for (int i = 0; i < 4; ++i) {
        int r = rb + w * 16 + lg * 4 + i;
        if (r < n) {
            #pragma unroll
            for (int ct = 0; ct < 4; ++ct)
                out[(size_t)r * NF + ct * 16 + lr] = f2bf(acc[ct][i]);
        }
    }
}

// ---------------- bucket sort (packed 4B pairs) ----------------
__global__ __launch_bounds__(256) void k_bsort2(const unsigned* __restrict__ pairs4,
                                                const int* __restrict__ bcnt,
                                                int* __restrict__ start, int* __restrict__ endp,
                                                int* __restrict__ adj,
                                                float* __restrict__ dis, int n) {
    __shared__ int cnt[256];
    __shared__ int cur[256];
    int b   = blockIdx.x;
    int nb  = b << 8;
    int nn  = n - nb; if (nn > 256) nn = 256;
    int ec  = bcnt[b]; if (ec > CAP) ec = CAP;
    int pbI = b * CAP;
    size_t pb = (size_t)pbI;
    int t = threadIdx.x;
    cnt[t] = 0;
    __syncthreads();
    for (int i = t; i < ec; i += 256)
        atomicAdd(&cnt[pairs4[pb + i] & 255u], 1);
    __syncthreads();
    int v = cnt[t];
    __syncthreads();
    for (int off = 1; off < 256; off <<= 1) {    // inclusive scan
        int u = (t >= off) ? cnt[t - off] : 0;
        __syncthreads();
        cnt[t] += u;
        __syncthreads();
    }
    int exc = cnt[t] - v;
    if (t < nn) {
        start[nb + t] = pbI + exc;
        endp[nb + t]  = pbI + exc + v;
        dis[nb + t]   = rsqrtf((float)(v + 1));
    }
    cur[t] = exc;
    __syncthreads();
    for (int i = t; i < ec; i += 256) {
        unsigned p = pairs4[pb + i];
        int off = atomicAdd(&cur[p & 255u], 1);
        adj[pbI + off] = (int)(p >> 8);
    }
}

// ---------------- FUSED gather-1 + layer-2 GEMM ----------------
// 1024 threads: phase 1 gathers 64 nodes (16 lanes/node, fp32 agg -> swizzled LDS);
// phase 2: 16 waves each compute one 16x16 MFMA tile of relu(agg+b1)@W2.
__global__ __launch_bounds__(1024) void k_gather_gemm(
        const unsigned short* __restrict__ g,
        const int* __restrict__ adj, const int* __restrict__ start,
        const int* __restrict__ endp, const float* __restrict__ dis,
        const unsigned short* __restrict__ wt2h_g, const unsigned short* __restrict__ wt2l_g,
        const float* __restrict__ b1,
        unsigned short* __restrict__ out, int n) {
    __shared__ float sA[64 * 64];            // 16 KB, swizzled 16B slots
    __shared__ unsigned short sWh[64 * 64];  // 8 KB
    __shared__ unsigned short sWl[64 * 64];  // 8 KB
    const int tid = threadIdx.x;
    const int rb = blockIdx.x * 64;

    stage_w<64>(wt2h_g, wt2l_g, sWh, sWl, tid, 1024);

    // ---- phase 1: gather (proven v4 structure) ----
    {
        int local = tid >> 4;          // 0..63
        int node  = rb + local;
        int fl = tid & 15;
        int gb = tid & 48;             // group base lane within wave
        float4 acc = make_float4(0.f, 0.f, 0.f, 0.f);
        if (node < n) {
            int s = start[node], e = endp[node];
            float dn = dis[node];
            uint2 v = *(const uint2*)&g[(size_t)node * NF + fl * 4];
            float2 pa = bfp2(v.x), pb = bfp2(v.y);
            acc = make_float4(pa.x * dn, pa.y * dn, pb.x * dn, pb.y * dn);
            for (int base = s; base < e; base += 16) {
                int m = e - base; if (m > 16) m = 16;
                int idx = (fl < m) ? adj[base + fl] : 0;
                for (int j = 0; j < m; ++j) {
                    int u = __shfl(idx, gb + j);   // source lane in own (active) group
                    float du = dis[u];
                    uint2 w = *(const uint2*)&g[(size_t)u * NF + fl * 4];
                    float2 q0 = bfp2(w.x), q1 = bfp2(w.y);
                    acc.x += q0.x * du; acc.y += q0.y * du;
                    acc.z += q1.x * du; acc.w += q1.y * du;
                }
            }
            acc.x *= dn; acc.y *= dn; acc.z *= dn; acc.w *= dn;
        }
        int d = local * 64 + 4 * (fl ^ (local & 15));   // float idx; slot=fl, swizzled
        *(float4*)&sA[d] = acc;
    }
    __syncthreads();

    // ---- phase 2: 16 waves; wave w: rows (w&3)*16.., col tile ct = w>>2 ----
    const int w = tid >> 6, l = tid & 63;
    const int lr = l & 15, lg = l >> 4;
    const int rg = (w & 3) * 16 + lr;      // A row within tile
    const int ct = w >> 2;
    f32x4 a4 = {};
    #pragma unroll
    for (int s = 0; s < 2; ++s) {
        float v8[8];
        #pragma unroll
        for (int half = 0; half < 2; ++half) {
            int slot = s * 8 + lg * 2 + half;
            int d = rg * 64 + 4 * (slot ^ (rg & 15));
            float4 t = *(const float4*)&sA[d];
            v8[half * 4 + 0] = t.x; v8[half * 4 + 1] = t.y;
            v8[half * 4 + 2] = t.z; v8[half * 4 + 3] = t.w;
        }
        unsigned short h8[8], l8[8];
        #pragma unroll
        for (int j = 0; j < 8; ++j) {
            float vv = fmaxf(v8[j] + b1[s * 32 + lg * 8 + j], 0.f);
            h8[j] = f2bf(vv);
            l8[j] = f2bf(vv - bf2f1(h8[j]));
        }
        const bf16x8 ah = *(const bf16x8*)h8;
        const bf16x8 al = *(const bf16x8*)l8;
        int col  = ct * 16 + lr;
        int boff = col * 64 + 8 * ((s * 4 + lg) ^ (col & 7));
        const bf16x8 bh = *(const bf16x8*)&sWh[boff];
        const bf16x8 bl = *(const bf16x8*)&sWl[boff];
        a4 = __builtin_amdgcn_mfma_f32_16x16x32_bf16(ah, bh, a4, 0, 0, 0);
        a4 = __builtin_amdgcn_mfma_f32_16x16x32_bf16(ah, bl, a4, 0, 0, 0);
        a4 = __builtin_amdgcn_mfma_f32_16x16x32_bf16(al, bh, a4, 0, 0, 0);
    }
    #pragma unroll
    for (int i = 0; i < 4; ++i) {
        int r = rb + (w & 3) * 16 + lg * 4 + i;
        if (r < n)
            out[(size_t)r * NF + ct * 16 + lr] = f2bf(a4[i]);
    }
}

// ---------------- gather + head fused ----------------
__global__ __launch_bounds__(256) void k_gather_final(const unsigned short* __restrict__ g,
                                                      const int* __restrict__ adj,
                                                      const int* __restrict__ start,
                                                      const int* __restrict__ endp,
                                                      const float* __restrict__ dis,
                                                      const float* __restrict__ b2,
                                                      const float* __restrict__ W3,
                                                      const float* __restrict__ b3,
                                                      float* __restrict__ out, int n) {
    int node = blockIdx.x * 16 + (threadIdx.x >> 4);
    int fl   = threadIdx.x & 15;
    int gb   = threadIdx.x & 48;
    if (node >= n) return;
    int s = start[node], e = endp[node];
    float dn = dis[node];
    uint2 v = *(const uint2*)&g[(size_t)node * NF + fl * 4];
    float2 pa = bfp2(v.x), pb = bfp2(v.y);
    float4 acc = make_float4(pa.x * dn, pa.y * dn, pb.x * dn, pb.y * dn);
    for (int base = s; base < e; base += 16) {
        int m = e - base; if (m > 16) m = 16;
        int idx = (fl < m) ? adj[base + fl] : 0;
        for (int j = 0; j < m; ++j) {
            int u = __shfl(idx, gb + j);
            float du = dis[u];
            uint2 w = *(const uint2*)&g[(size_t)u * NF + fl * 4];
            float2 q0 = bfp2(w.x), q1 = bfp2(w.y);
            acc.x += q0.x * du; acc.y += q0.y * du;
            acc.z += q1.x * du; acc.w += q1.y * du;
        }
    }
    const float4 bb = *(const float4*)&b2[fl * 4];
    const float4 ww = *(const float4*)&W3[fl * 4];
    float r = fmaxf(acc.x * dn + bb.x, 0.f) * ww.x
            + fmaxf(acc.y * dn + bb.y, 0.f) * ww.y
            + fmaxf(acc.z * dn + bb.z, 0.f) * ww.z
            + fmaxf(acc.w * dn + bb.w, 0.f) * ww.w;
    #pragma unroll
    for (int off = 8; off > 0; off >>= 1) r += __shfl_down(r, off, 16);
    if (fl == 0) out[node] = r + b3[0];
}

extern "C" void kernel_launch(void* const* d_in, const int* in_sizes, int n_in,
                              void* d_out, int out_size, void* d_ws, size_t ws_size,
                              hipStream_t stream) {
    const float* x  = (const float*)d_in[0];
    const int*   ei = (const int*)d_in[1];   // int32 (JAX x64-disabled)
    const float* W1 = (const float*)d_in[2];
    const float* b1 = (const float*)d_in[3];
    const float* W2 = (const float*)d_in[4];
    const float* b2 = (const float*)d_in[5];
    const float* W3 = (const float*)d_in[6];
    const float* b3 = (const float*)d_in[7];
    float* out = (float*)d_out;

    const int n = out_size;           // 100000
    const int E = in_sizes[1] / 2;    // 1200000
    const int* src = ei;
    const int* dst = ei + E;
    const int ns  = (n + 255) & ~255;
    const int nbk = (n + 255) >> 8;   // 391

    char* w = (char*)d_ws;
    float* dis   = (float*)w;  w += (size_t)ns * 4;
    int*   start = (int*)w;    w += (size_t)ns * 4;
    int*   endp  = (int*)w;    w += (size_t)ns * 4;
    int*   adj   = (int*)w;    w += (size_t)nbk * CAP * 4;        // 6.4 MB slack layout
    int*   bcnt  = (int*)w;    w += NBKMAX * 4;
    unsigned short* wt1h = (unsigned short*)w;  w += 64 * 128 * 2;
    unsigned short* wt1l = (unsigned short*)w;  w += 64 * 128 * 2;
    unsigned short* wt2h = (unsigned short*)w;  w += 64 * 64 * 2;
    unsigned short* wt2l = (unsigned short*)w;  w += 64 * 64 * 2;
    unsigned short* gbuf1 = (unsigned short*)w;  w += (size_t)n * NF * 2;  // 12.8 MB
    unsigned short* gbuf2 = (unsigned short*)w;  w += (size_t)n * NF * 2;  // 12.8 MB
    unsigned* pairs4 = (unsigned*)w;  // 6.4 MB packed slack pairs

    const int B = 256;
    const int nscat = (E + CHUNK - 1) / CHUNK;     // 293
    const int ngemm = (n + 63) / 64;               // 1563

    // prep (zero bcnt + W split), then CSR-scatter overlapped with layer-1 GEMM
    k_prep<<<(512 + 128 * 64 + 64 * 64 + B - 1) / B, B, 0, stream>>>(
        bcnt, nbk, W1, wt1h, wt1l, W2, wt2h, wt2l);
    k_scat_gemm<<<nscat + ngemm, B, 0, stream>>>(
        src, dst, bcnt, pairs4, E, nbk, nscat, x, wt1h, wt1l, gbuf1, n);
    k_bsort2<<<nbk, B, 0, stream>>>(pairs4, bcnt, start, endp, adj, dis, n);

    // ----- gather-1 + layer-2 GEMM fused -----
    k_gather_gemm<<<ngemm, 1024, 0, stream>>>(
        gbuf1, adj, start, endp, dis, wt2h, wt2l, b1, gbuf2, n);

    // ----- layer-2 aggregation + head -----
    k_gather_final<<<(n + 15) / 16, B, 0, stream>>>(gbuf2, adj, start, endp, dis, b2, W3, b3, out, n);
}

// Round 18
// 128.838 us; speedup vs baseline: 1.0423x; 1.0423x over previous
//
#include <hip/hip_runtime.h>

#define NF 64
#define NBKMAX 512   // buckets of 256 nodes; n=100K -> 391 buckets
#define CHUNK 4096
#define CAP   4096   // slack capacity per bucket (mean 3070, +18 sigma)

typedef __attribute__((ext_vector_type(8))) short bf16x8;
typedef __attribute__((ext_vector_type(4))) float f32x4;

// bf16 helpers (RNE)
__device__ __forceinline__ unsigned short f2bf(float f) {
    union { float f; unsigned u; } c; c.f = f;
    unsigned u = c.u;
    return (unsigned short)((u + 0x7FFFu + ((u >> 16) & 1u)) >> 16);
}
__device__ __forceinline__ float bf2f1(unsigned short v) {
    union { unsigned u; float f; } c; c.u = ((unsigned)v) << 16;
    return c.f;
}
__device__ __forceinline__ float2 bfp2(unsigned v) {
    union { unsigned u; float f; } lo, hi;
    lo.u = v << 16;
    hi.u = v & 0xffff0000u;
    return make_float2(lo.f, hi.f);
}

// ---------------- prep: zero bcnt + W1/W2 hi/lo transpose-split ----------------
__global__ __launch_bounds__(256) void k_prep(int* __restrict__ bcnt, int nbk,
                                              const float* __restrict__ W1,
                                              unsigned short* __restrict__ wt1h,
                                              unsigned short* __restrict__ wt1l,
                                              const float* __restrict__ W2,
                                              unsigned short* __restrict__ wt2h,
                                              unsigned short* __restrict__ wt2l) {
    int idx = blockIdx.x * 256 + threadIdx.x;
    if (idx < 512) {
        if (idx < nbk) bcnt[idx] = 0;
    } else if (idx < 512 + 128 * 64) {
        int e = idx - 512;                 // W1: [128][64]
        int k = e >> 6, col = e & 63;
        float w = W1[e];
        unsigned short h = f2bf(w);
        wt1h[col * 128 + k] = h;
        wt1l[col * 128 + k] = f2bf(w - bf2f1(h));
    } else if (idx < 512 + 128 * 64 + 64 * 64) {
        int e = idx - 512 - 128 * 64;      // W2: [64][64]
        int k = e >> 6, col = e & 63;
        float w = W2[e];
        unsigned short h = f2bf(w);
        wt2h[col * 64 + k] = h;
        wt2l[col * 64 + k] = f2bf(w - bf2f1(h));
    }
}

// ---------------- GEMM core: A direct global->reg (no LDS, no per-step barrier) -------
__device__ __forceinline__ void load8f(const float* A, bool ok, size_t off, float* v) {
    if (ok) {
        float4 a = *(const float4*)&A[off];
        float4 b = *(const float4*)&A[off + 4];
        v[0]=a.x; v[1]=a.y; v[2]=a.z; v[3]=a.w;
        v[4]=b.x; v[5]=b.y; v[6]=b.z; v[7]=b.w;
    } else { for (int j = 0; j < 8; ++j) v[j] = 0.f; }
}
__device__ __forceinline__ void load8f(const unsigned short* A, bool ok, size_t off, float* v) {
    if (ok) {
        uint4 u = *(const uint4*)&A[off];
        float2 p0 = bfp2(u.x), p1 = bfp2(u.y), p2 = bfp2(u.z), p3 = bfp2(u.w);
        v[0]=p0.x; v[1]=p0.y; v[2]=p1.x; v[3]=p1.y;
        v[4]=p2.x; v[5]=p2.y; v[6]=p3.x; v[7]=p3.y;
    } else { for (int j = 0; j < 8; ++j) v[j] = 0.f; }
}

template<int K>
__device__ __forceinline__ void stage_w(const unsigned short* __restrict__ Wt_hi_g,
                                        const unsigned short* __restrict__ Wt_lo_g,
                                        unsigned short* __restrict__ sWh,
                                        unsigned short* __restrict__ sWl, int tid) {
    constexpr int KS = K / 8, SM = KS - 1;
    for (int idx = tid; idx < 64 * KS; idx += 256) {
        int col = idx / KS, slot = idx % KS;
        int d = col * K + 8 * (slot ^ (col & SM));
        *(uint4*)&sWh[d] = *(const uint4*)&Wt_hi_g[col * K + slot * 8];
        *(uint4*)&sWl[d] = *(const uint4*)&Wt_lo_g[col * K + slot * 8];
    }
}

template<int K, bool HASBIAS, typename AT>
__device__ __forceinline__ void gemm_core(const AT* __restrict__ A,
                                          const unsigned short* __restrict__ sWh,
                                          const unsigned short* __restrict__ sWl,
                                          const float* __restrict__ bias_in,
                                          unsigned short* __restrict__ out,
                                          int n, int rb, int tid) {
    constexpr int KS = K / 8, SM = KS - 1, NS = K / 32;
    const int w = tid >> 6, l = tid & 63;
    const int lr = l & 15, lg = l >> 4;
    const int arow = rb + w * 16 + lr;
    const bool ok = arow < n;

    // issue ALL A loads up-front (deep MLP), straight to registers
    float v[NS][8];
    #pragma unroll
    for (int s = 0; s < NS; ++s)
        load8f(A, ok, (size_t)arow * K + s * 32 + lg * 8, v[s]);

    f32x4 acc[4] = {};
    #pragma unroll
    for (int s = 0; s < NS; ++s) {
        if (HASBIAS) {
            #pragma unroll
            for (int j = 0; j < 8; ++j)
                v[s][j] = fmaxf(v[s][j] + bias_in[s * 32 + lg * 8 + j], 0.f);
        }
        unsigned short h8[8], l8[8];
        #pragma unroll
        for (int j = 0; j < 8; ++j) {
            h8[j] = f2bf(v[s][j]);
            l8[j] = f2bf(v[s][j] - bf2f1(h8[j]));
        }
        const bf16x8 ah = *(const bf16x8*)h8;
        const bf16x8 al = *(const bf16x8*)l8;
        #pragma unroll
        for (int ct = 0; ct < 4; ++ct) {
            int col  = ct * 16 + lr;
            int boff = col * K + 8 * ((s * 4 + lg) ^ (col & SM));
            const bf16x8 bh = *(const bf16x8*)&sWh[boff];
            const bf16x8 bl = *(const bf16x8*)&sWl[boff];
            acc[ct] = __builtin_amdgcn_mfma_f32_16x16x32_bf16(ah, bh, acc[ct], 0, 0, 0);
            acc[ct] = __builtin_amdgcn_mfma_f32_16x16x32_bf16(ah, bl, acc[ct], 0, 0, 0);
            acc[ct] = __builtin_amdgcn_mfma_f32_16x16x32_bf16(al, bh, acc[ct], 0, 0, 0);
        }
    }

    // epilogue: D row = lg*4 + i, col = lr  [m89]
    #pragma unroll
    for (int i = 0; i < 4; ++i) {
        int r = rb + w * 16 + lg * 4 + i;
        if (r < n) {
            #pragma unroll
            for (int ct = 0; ct < 4; ++ct)
                out[(size_t)r * NF + ct * 16 + lr] = f2bf(acc[ct][i]);
        }
    }
}

// ---------------- fused: edge bucket-scatter (packed 4B) PARALLEL WITH mgemm<128> -----
struct ScatS {
    unsigned stage[CHUNK];          // (src<<8)|(dst&255)
    unsigned short stb[CHUNK];      // bucket = dst>>8
    int hist[NBKMAX];
    int base[NBKMAX];
};                                   // 28 KB
struct GemmS {
    unsigned short sWh[64 * 128];    // 16 KB
    unsigned short sWl[64 * 128];    // 16 KB
};
union USmem { ScatS s; GemmS g; };   // 32 KB -> 5 blocks/CU

__global__ __launch_bounds__(256) void k_scat_gemm(
        const int* __restrict__ src, const int* __restrict__ dst,
        int* __restrict__ bcnt, unsigned* __restrict__ pairs4, int E, int nbk, int nscat,
        const float* __restrict__ A,
        const unsigned short* __restrict__ Wt_hi_g, const unsigned short* __restrict__ Wt_lo_g,
        unsigned short* __restrict__ out, int n) {
    __shared__ USmem u;
    const int tid = threadIdx.x;

    if ((int)blockIdx.x < nscat) {
        // ---- scatter path ----
        int e0 = blockIdx.x * CHUNK;
        int cnt = E - e0; if (cnt > CHUNK) cnt = CHUNK;
        for (int i = tid; i < nbk; i += 256) u.s.hist[i] = 0;
        __syncthreads();
        for (int i = tid; i < cnt; i += 256) {
            int s = src[e0 + i], d = dst[e0 + i];
            u.s.stage[i] = ((unsigned)s << 8) | ((unsigned)d & 255u);
            u.s.stb[i]   = (unsigned short)(((unsigned)d) >> 8);
            atomicAdd(&u.s.hist[((unsigned)d) >> 8], 1);
        }
        __syncthreads();
        for (int i = tid; i < nbk; i += 256) {
            int c = u.s.hist[i];
            u.s.base[i] = c ? atomicAdd(&bcnt[i], c) : 0;
            u.s.hist[i] = 0;   // reuse as local cursor
        }
        __syncthreads();
        for (int i = tid; i < cnt; i += 256) {
            int b = u.s.stb[i];
            int off = u.s.base[b] + atomicAdd(&u.s.hist[b], 1);
            if (off < CAP) pairs4[(size_t)b * CAP + off] = u.s.stage[i];
        }
        return;
    }

    // ---- mgemm<128,float> path ----
    const int rb = ((int)blockIdx.x - nscat) * 64;
    stage_w<128>(Wt_hi_g, Wt_lo_g, u.g.sWh, u.g.sWl, tid);
    __syncthreads();
    gemm_core<128, false>(A, u.g.sWh, u.g.sWl, nullptr, out, n, rb, tid);
}

// ---------------- bucket sort (packed 4B pairs) ----------------
__global__ __launch_bounds__(256) void k_bsort2(const unsigned* __restrict__ pairs4,
                                                const int* __restrict__ bcnt,
                                                int* __restrict__ start, int* __restrict__ endp,
                                                int* __restrict__ adj,
                                                float* __restrict__ dis, int n) {
    __shared__ int cnt[256];
    __shared__ int cur[256];
    int b   = blockIdx.x;
    int nb  = b << 8;
    int nn  = n - nb; if (nn > 256) nn = 256;
    int ec  = bcnt[b]; if (ec > CAP) ec = CAP;
    int pbI = b * CAP;
    size_t pb = (size_t)pbI;
    int t = threadIdx.x;
    cnt[t] = 0;
    __syncthreads();
    for (int i = t; i < ec; i += 256)
        atomicAdd(&cnt[pairs4[pb + i] & 255u], 1);
    __syncthreads();
    int v = cnt[t];
    __syncthreads();
    for (int off = 1; off < 256; off <<= 1) {    // inclusive scan
        int u = (t >= off) ? cnt[t - off] : 0;
        __syncthreads();
        cnt[t] += u;
        __syncthreads();
    }
    int exc = cnt[t] - v;
    if (t < nn) {
        start[nb + t] = pbI + exc;
        endp[nb + t]  = pbI + exc + v;
        dis[nb + t]   = rsqrtf((float)(v + 1));
    }
    cur[t] = exc;
    __syncthreads();
    for (int i = t; i < ec; i += 256) {
        unsigned p = pairs4[pb + i];
        int off = atomicAdd(&cur[p & 255u], 1);
        adj[pbI + off] = (int)(p >> 8);
    }
}

// ---------------- MFMA GEMM layer 2 (bf16 A, relu(A+b1)) ----------------
__global__ __launch_bounds__(256) void k_mgemm64(const unsigned short* __restrict__ A,
                                                 const unsigned short* __restrict__ Wt_hi_g,
                                                 const unsigned short* __restrict__ Wt_lo_g,
                                                 const float* __restrict__ bias_in,
                                                 unsigned short* __restrict__ out, int n) {
    __shared__ unsigned short sWh[64 * 64];
    __shared__ unsigned short sWl[64 * 64];
    const int tid = threadIdx.x;
    const int rb = blockIdx.x * 64;
    stage_w<64>(Wt_hi_g, Wt_lo_g, sWh, sWl, tid);
    __syncthreads();
    gemm_core<64, true>(A, sWh, sWl, bias_in, out, n, rb, tid);
}

// ---------------- gather v4 + per-edge dis: agg = dis[d]*(dis[d]*g[d] + sum dis[u]*g[u]) ------
__global__ __launch_bounds__(256) void k_gather(const unsigned short* __restrict__ g,
                                                const int* __restrict__ adj,
                                                const int* __restrict__ start,
                                                const int* __restrict__ endp,
                                                const float* __restrict__ dis,
                                                unsigned short* __restrict__ agg, int n) {
    int node = blockIdx.x * 16 + (threadIdx.x >> 4);
    int fl   = threadIdx.x & 15;
    int gb   = threadIdx.x & 48;   // group base lane within wave
    if (node >= n) return;
    int s = start[node], e = endp[node];
    float dn = dis[node];
    uint2 v = *(const uint2*)&g[(size_t)node * NF + fl * 4];   // self-loop
    float2 pa = bfp2(v.x), pb = bfp2(v.y);
    float4 acc = make_float4(pa.x * dn, pa.y * dn, pb.x * dn, pb.y * dn);
    for (int base = s; base < e; base += 16) {
        int m = e - base; if (m > 16) m = 16;
        int idx = (fl < m) ? adj[base + fl] : 0;
        for (int j = 0; j < m; ++j) {
            int u = __shfl(idx, gb + j);   // source lane in own (active) group
            float du = dis[u];
            uint2 w = *(const uint2*)&g[(size_t)u * NF + fl * 4];
            float2 q0 = bfp2(w.x), q1 = bfp2(w.y);
            acc.x += q0.x * du; acc.y += q0.y * du;
            acc.z += q1.x * du; acc.w += q1.y * du;
        }
    }
    ushort4 o;
    o.x = f2bf(acc.x * dn);
    o.y = f2bf(acc.y * dn);
    o.z = f2bf(acc.z * dn);
    o.w = f2bf(acc.w * dn);
    *(ushort4*)&agg[(size_t)node * NF + fl * 4] = o;
}

// ---------------- gather + head fused ----------------
__global__ __launch_bounds__(256) void k_gather_final(const unsigned short* __restrict__ g,
                                                      const int* __restrict__ adj,
                                                      const int* __restrict__ start,
                                                      const int* __restrict__ endp,
                                                      const float* __restrict__ dis,
                                                      const float* __restrict__ b2,
                                                      const float* __restrict__ W3,
                                                      const float* __restrict__ b3,
                                                      float* __restrict__ out, int n) {
    int node = blockIdx.x * 16 + (threadIdx.x >> 4);
    int fl   = threadIdx.x & 15;
    int gb   = threadIdx.x & 48;
    if (node >= n) return;
    int s = start[node], e = endp[node];
    float dn = dis[node];
    uint2 v = *(const uint2*)&g[(size_t)node * NF + fl * 4];
    float2 pa = bfp2(v.x), pb = bfp2(v.y);
    float4 acc = make_float4(pa.x * dn, pa.y * dn, pb.x * dn, pb.y * dn);
    for (int base = s; base < e; base += 16) {
        int m = e - base; if (m > 16) m = 16;
        int idx = (fl < m) ? adj[base + fl] : 0;
        for (int j = 0; j < m; ++j) {
            int u = __shfl(idx, gb + j);
            float du = dis[u];
            uint2 w = *(const uint2*)&g[(size_t)u * NF + fl * 4];
            float2 q0 = bfp2(w.x), q1 = bfp2(w.y);
            acc.x += q0.x * du; acc.y += q0.y * du;
            acc.z += q1.x * du; acc.w += q1.y * du;
        }
    }
    const float4 bb = *(const float4*)&b2[fl * 4];
    const float4 ww = *(const float4*)&W3[fl * 4];
    float r = fmaxf(acc.x * dn + bb.x, 0.f) * ww.x
            + fmaxf(acc.y * dn + bb.y, 0.f) * ww.y
            + fmaxf(acc.z * dn + bb.z, 0.f) * ww.z
            + fmaxf(acc.w * dn + bb.w, 0.f) * ww.w;
    #pragma unroll
    for (int off = 8; off > 0; off >>= 1) r += __shfl_down(r, off, 16);
    if (fl == 0) out[node] = r + b3[0];
}

extern "C" void kernel_launch(void* const* d_in, const int* in_sizes, int n_in,
                              void* d_out, int out_size, void* d_ws, size_t ws_size,
                              hipStream_t stream) {
    const float* x  = (const float*)d_in[0];
    const int*   ei = (const int*)d_in[1];   // int32 (JAX x64-disabled)
    const float* W1 = (const float*)d_in[2];
    const float* b1 = (const float*)d_in[3];
    const float* W2 = (const float*)d_in[4];
    const float* b2 = (const float*)d_in[5];
    const float* W3 = (const float*)d_in[6];
    const float* b3 = (const float*)d_in[7];
    float* out = (float*)d_out;

    const int n = out_size;           // 100000
    const int E = in_sizes[1] / 2;    // 1200000
    const int* src = ei;
    const int* dst = ei + E;
    const int ns  = (n + 255) & ~255;
    const int nbk = (n + 255) >> 8;   // 391

    char* w = (char*)d_ws;
    float* dis   = (float*)w;  w += (size_t)ns * 4;
    int*   start = (int*)w;    w += (size_t)ns * 4;
    int*   endp  = (int*)w;    w += (size_t)ns * 4;
    int*   adj   = (int*)w;    w += (size_t)nbk * CAP * 4;        // 6.4 MB slack layout
    int*   bcnt  = (int*)w;    w += NBKMAX * 4;
    unsigned short* wt1h = (unsigned short*)w;  w += 64 * 128 * 2;
    unsigned short* wt1l = (unsigned short*)w;  w += 64 * 128 * 2;
    unsigned short* wt2h = (unsigned short*)w;  w += 64 * 64 * 2;
    unsigned short* wt2l = (unsigned short*)w;  w += 64 * 64 * 2;
    unsigned short* gbuf1 = (unsigned short*)w;  w += (size_t)n * NF * 2;  // 12.8 MB
    unsigned short* gbuf2 = (unsigned short*)w;  w += (size_t)n * NF * 2;  // 12.8 MB
    unsigned short* aggb  = (unsigned short*)w;  w += (size_t)n * NF * 2;  // 12.8 MB (bf16 agg)
    unsigned* pairs4 = (unsigned*)w;  // 6.4 MB packed slack pairs

    const int B = 256;
    const int nscat = (E + CHUNK - 1) / CHUNK;     // 293
    const int ngemm = (n + 63) / 64;               // 1563

    // prep (zero bcnt + W split), then CSR-scatter overlapped with layer-1 GEMM
    k_prep<<<(512 + 128 * 64 + 64 * 64 + B - 1) / B, B, 0, stream>>>(
        bcnt, nbk, W1, wt1h, wt1l, W2, wt2h, wt2l);
    k_scat_gemm<<<nscat + ngemm, B, 0, stream>>>(
        src, dst, bcnt, pairs4, E, nbk, nscat, x, wt1h, wt1l, gbuf1, n);
    k_bsort2<<<nbk, B, 0, stream>>>(pairs4, bcnt, start, endp, adj, dis, n);

    // ----- layer 1 aggregation -----
    k_gather<<<(n + 15) / 16, B, 0, stream>>>(gbuf1, adj, start, endp, dis, aggb, n);

    // ----- layer 2 + head -----
    k_mgemm64<<<ngemm, B, 0, stream>>>(aggb, wt2h, wt2l, b1, gbuf2, n);
    k_gather_final<<<(n + 15) / 16, B, 0, stream>>>(gbuf2, adj, start, endp, dis, b2, W3, b3, out, n);
}